// Round 2
// baseline (275.591 us; speedup 1.0000x reference)
//
#include <hip/hip_runtime.h>

#define N_NODES  100000
#define N_EDGES  1600000
#define IN_CH    128
#define HID      32
#define N_GRAPHS 64

#define NBIN   391            // bins of 256 dst nodes: bin = dst >> 8
#define CHUNK  4096           // edges per multisplit block; grid = 391
#define MGRID  391            // ceil(1.6M / 4096)
#define STG    5120           // csr2 per-bin staging capacity
#define PLN    800000         // uints per bf16 channel-plane (N_NODES * 8)

// workspace layout (4-byte element offsets) — total ~26.4 MB
#define OFF_B      0          // Bu1: 2 planes x 800K uints; H[391*391] aliases head (dead before gemm1)
#define OFF_EDGEPK 3200000    // int[1,600,000]; Bu2 planes alias after csr2
#define OFF_CSR    4800000    // int[1,600,000]
#define OFF_COLT   6400000    // int[391]
#define OFF_BINB   6400391    // int[392]
#define OFF_ROWPTR 6400784    // int[100,001]
#define OFF_DINV   6500785    // float[100,000]
#define OFF_GS     6600800    // float[64*32] gsum + float[64] cnt

typedef float v2f __attribute__((ext_vector_type(2)));

// bf16 pack (RNE) / unpack helpers
__device__ __forceinline__ unsigned bfr(float f) {
    unsigned u = __float_as_uint(f);
    u += 0x7fffu + ((u >> 16) & 1u);
    return u >> 16;
}
__device__ __forceinline__ float bflo(unsigned w) { return __uint_as_float(w << 16); }
__device__ __forceinline__ float bfhi(unsigned w) { return __uint_as_float(w & 0xffff0000u); }

// ---------- phase 1: per-(bin, wg) histogram ----------
__global__ __launch_bounds__(512) void hist_kernel(const int* __restrict__ dst,
                                                   int* __restrict__ H) {
    __shared__ int s[512];
    int t = threadIdx.x, wg = blockIdx.x;
    s[t] = 0;
    __syncthreads();
    int e0 = wg * CHUNK, e1 = min(e0 + CHUNK, N_EDGES);
    for (int e = e0 + t; e < e1; e += 512) {
        int d = dst[e];
        if ((unsigned)d < N_NODES) atomicAdd(&s[d >> 8], 1);
    }
    __syncthreads();
    if (t < NBIN) H[t * MGRID + wg] = s[t];
}

// ---------- phase 2a ----------
__global__ __launch_bounds__(512) void scanrow_kernel(int* __restrict__ H,
                                                      int* __restrict__ colT) {
    __shared__ int s[512];
    int t = threadIdx.x, bin = blockIdx.x;
    s[t] = (t < MGRID) ? H[bin * MGRID + t] : 0;
    __syncthreads();
    for (int off = 1; off < 512; off <<= 1) {
        int v = (t >= off) ? s[t - off] : 0;
        __syncthreads();
        if (t >= off) s[t] += v;
        __syncthreads();
    }
    if (t < MGRID) H[bin * MGRID + t] = t ? s[t - 1] : 0;
    if (t == 0) colT[bin] = s[MGRID - 1];
}

// ---------- phase 2b ----------
__global__ __launch_bounds__(512) void scanbase_kernel(const int* __restrict__ colT,
                                                       int* __restrict__ binB,
                                                       int* __restrict__ row_ptr) {
    __shared__ int s[512];
    int t = threadIdx.x;
    s[t] = (t < NBIN) ? colT[t] : 0;
    __syncthreads();
    for (int off = 1; off < 512; off <<= 1) {
        int v = (t >= off) ? s[t - off] : 0;
        __syncthreads();
        if (t >= off) s[t] += v;
        __syncthreads();
    }
    if (t < NBIN) binB[t] = t ? s[t - 1] : 0;
    if (t == 0) { binB[NBIN] = s[NBIN - 1]; row_ptr[N_NODES] = s[NBIN - 1]; }
}

// ---------- phase 3: bin-grouped scatter, LDS-staged coalesced flush ----------
__global__ __launch_bounds__(512) void msplit_kernel(const int* __restrict__ src,
                                                     const int* __restrict__ dst,
                                                     const int* __restrict__ H,
                                                     const int* __restrict__ binB,
                                                     int* __restrict__ edgepk) {
    __shared__ int s[512];
    __shared__ int cur[NBIN];
    __shared__ int gb[NBIN];
    __shared__ int stage[CHUNK];
    __shared__ int gof[CHUNK];
    int t = threadIdx.x, wg = blockIdx.x;
    s[t] = 0;
    __syncthreads();
    int e0 = wg * CHUNK, e1 = min(e0 + CHUNK, N_EDGES);
    for (int e = e0 + t; e < e1; e += 512) {
        int d = dst[e];
        if ((unsigned)d < N_NODES) atomicAdd(&s[d >> 8], 1);
    }
    __syncthreads();
    for (int off = 1; off < 512; off <<= 1) {
        int v = (t >= off) ? s[t - off] : 0;
        __syncthreads();
        if (t >= off) s[t] += v;
        __syncthreads();
    }
    if (t < NBIN) {
        int lo = t ? s[t - 1] : 0;
        cur[t] = lo;
        gb[t] = binB[t] + H[t * MGRID + wg] - lo;
    }
    __syncthreads();
    for (int e = e0 + t; e < e1; e += 512) {
        int d = dst[e];
        if ((unsigned)d < N_NODES) {
            int b = d >> 8;
            int p = atomicAdd(&cur[b], 1);
            stage[p] = (src[e] << 8) | (d & 255);
            gof[p] = gb[b];
        }
    }
    __syncthreads();
    int total = s[511];
    for (int p = t; p < total; p += 512)
        edgepk[gof[p] + p] = stage[p];
}

// ---------- phase 4: within-bin reorder -> CSR + dinv/row_ptr ----------
__global__ __launch_bounds__(256) void csr2_kernel(const int* __restrict__ edgepk,
                                                   const int* __restrict__ binB,
                                                   int* __restrict__ row_ptr,
                                                   float* __restrict__ dinv,
                                                   int* __restrict__ csr) {
    __shared__ int cnt[256], s[256], cur[256];
    __shared__ int stage[STG];
    int t = threadIdx.x, bin = blockIdx.x;
    int ebase = binB[bin], eend = binB[bin + 1];
    int n = eend - ebase;
    cnt[t] = 0;
    __syncthreads();
    for (int p = ebase + t; p < eend; p += 256)
        atomicAdd(&cnt[edgepk[p] & 255], 1);
    __syncthreads();
    s[t] = cnt[t];
    __syncthreads();
    for (int off = 1; off < 256; off <<= 1) {
        int v = (t >= off) ? s[t - off] : 0;
        __syncthreads();
        if (t >= off) s[t] += v;
        __syncthreads();
    }
    int excl = t ? s[t - 1] : 0;
    int node = (bin << 8) + t;
    if (node < N_NODES) {
        dinv[node] = rsqrtf((float)(cnt[t] + 1));
        row_ptr[node] = ebase + excl;
    }
    cur[t] = excl;
    __syncthreads();
    for (int p = ebase + t; p < eend; p += 256) {
        int w = edgepk[p];
        int l = atomicAdd(&cur[w & 255], 1);
        int sv = w >> 8;
        if (l < STG) stage[l] = sv;
        else csr[ebase + l] = sv;
    }
    __syncthreads();
    int lim = min(n, STG);
    for (int l = t; l < lim; l += 256)
        csr[ebase + l] = stage[l];
}

// ---------- B(bf16, 2 channel-planes) = (x @ W1) * dinv[row] ----------
#define XS1 132               // 128 + 4 pad
__global__ __launch_bounds__(256) void gemm1_kernel(const float* __restrict__ x,
                                                    const float* __restrict__ W1,
                                                    const float* __restrict__ dinv,
                                                    unsigned* __restrict__ Bu) {
    __shared__ float Wl[IN_CH * HID];   // 16 KB
    __shared__ float xs[32 * XS1];      // 16.9 KB
    int tid = threadIdx.x;
    for (int j = tid; j < IN_CH * HID / 4; j += 256)
        ((float4*)Wl)[j] = ((const float4*)W1)[j];
    int row0 = blockIdx.x * 32;         // 100000 % 32 == 0
    const float4* x4 = (const float4*)(x + (size_t)row0 * IN_CH);
    for (int j = tid; j < 32 * IN_CH / 4; j += 256) {
        int r = j >> 5, k4 = j & 31;
        ((float4*)&xs[r * XS1])[k4] = x4[j];
    }
    __syncthreads();
    int r = tid >> 3, cg = (tid & 7) * 4;
    const float* xr = &xs[r * XS1];
    float4 acc = {0.f, 0.f, 0.f, 0.f};
    #pragma unroll 8
    for (int k = 0; k < IN_CH; ++k) {
        float xv = xr[k];
        float4 w = *(const float4*)&Wl[k * HID + cg];
        acc.x += xv * w.x; acc.y += xv * w.y; acc.z += xv * w.z; acc.w += xv * w.w;
    }
    int row = row0 + r;
    float dv = dinv[row];
    uint2 p;
    p.x = bfr(acc.x * dv) | (bfr(acc.y * dv) << 16);
    p.y = bfr(acc.z * dv) | (bfr(acc.w * dv) << 16);
    int c8 = tid & 7;   // owns channels 4*c8..4*c8+3 -> plane c8>>2, uints 2*(c8&3)..+1
    *(uint2*)(Bu + (size_t)(c8 >> 2) * PLN + (size_t)row * 8 + (c8 & 3) * 2) = p;
}

// ---------- B(bf16, 2 planes) = (in @ W2) * dinv[row] ----------
#define XS2 36                // 32 + 4 pad
__global__ __launch_bounds__(256) void gemm2_kernel(const float* __restrict__ in,
                                                    const float* __restrict__ W2,
                                                    const float* __restrict__ dinv,
                                                    unsigned* __restrict__ Bu) {
    __shared__ float Wl[HID * HID];     // 4 KB
    __shared__ float xs[32 * XS2];      // 4.6 KB
    int tid = threadIdx.x;
    ((float4*)Wl)[tid] = ((const float4*)W2)[tid];
    int row0 = blockIdx.x * 32;
    const float4* in4 = (const float4*)(in + (size_t)row0 * HID);
    {
        int r = tid >> 3, k4 = tid & 7;
        ((float4*)&xs[r * XS2])[k4] = in4[tid];
    }
    __syncthreads();
    int r = tid >> 3, cg = (tid & 7) * 4;
    const float* xr = &xs[r * XS2];
    float4 acc = {0.f, 0.f, 0.f, 0.f};
    #pragma unroll
    for (int k = 0; k < HID; ++k) {
        float xv = xr[k];
        float4 w = *(const float4*)&Wl[k * HID + cg];
        acc.x += xv * w.x; acc.y += xv * w.y; acc.z += xv * w.z; acc.w += xv * w.w;
    }
    int row = row0 + r;
    float dv = dinv[row];
    uint2 p;
    p.x = bfr(acc.x * dv) | (bfr(acc.y * dv) << 16);
    p.y = bfr(acc.z * dv) | (bfr(acc.w * dv) << 16);
    int c8 = tid & 7;
    *(uint2*)(Bu + (size_t)(c8 >> 2) * PLN + (size_t)row * 8 + (c8 & 3) * 2) = p;
}

// ---------- gather pass over ONE 3.2MB channel-plane (L2-resident) ----------
// 8 lanes/node (2 ch each), 32 nodes/block. csr streamed nontemporal so it
// doesn't evict the hot plane; h-half written nontemporal.
__global__ __launch_bounds__(256) void gather_kernel(const unsigned* __restrict__ Bp,
                                                     const int* __restrict__ csr,
                                                     const int* __restrict__ row_ptr,
                                                     const float* __restrict__ dinv,
                                                     const float* __restrict__ bias,
                                                     float* __restrict__ outp,
                                                     int relu) {
    int tid = threadIdx.x;
    int node = blockIdx.x * 32 + (tid >> 3);   // grid 3125 -> exactly 100000
    int c = tid & 7;
    unsigned ws0 = Bp[(size_t)node * 8 + c];
    float a0 = bflo(ws0), a1 = bfhi(ws0);
    int j = row_ptr[node], re = row_ptr[node + 1];
    for (; j + 8 <= re; j += 8) {
        int s0 = __builtin_nontemporal_load(csr + j + 0);
        int s1 = __builtin_nontemporal_load(csr + j + 1);
        int s2 = __builtin_nontemporal_load(csr + j + 2);
        int s3 = __builtin_nontemporal_load(csr + j + 3);
        int s4 = __builtin_nontemporal_load(csr + j + 4);
        int s5 = __builtin_nontemporal_load(csr + j + 5);
        int s6 = __builtin_nontemporal_load(csr + j + 6);
        int s7 = __builtin_nontemporal_load(csr + j + 7);
        unsigned w0 = Bp[(size_t)s0 * 8 + c], w1 = Bp[(size_t)s1 * 8 + c];
        unsigned w2 = Bp[(size_t)s2 * 8 + c], w3 = Bp[(size_t)s3 * 8 + c];
        unsigned w4 = Bp[(size_t)s4 * 8 + c], w5 = Bp[(size_t)s5 * 8 + c];
        unsigned w6 = Bp[(size_t)s6 * 8 + c], w7 = Bp[(size_t)s7 * 8 + c];
        a0 += ((bflo(w0) + bflo(w1)) + (bflo(w2) + bflo(w3)))
            + ((bflo(w4) + bflo(w5)) + (bflo(w6) + bflo(w7)));
        a1 += ((bfhi(w0) + bfhi(w1)) + (bfhi(w2) + bfhi(w3)))
            + ((bfhi(w4) + bfhi(w5)) + (bfhi(w6) + bfhi(w7)));
    }
    if (j + 4 <= re) {
        int s0 = __builtin_nontemporal_load(csr + j + 0);
        int s1 = __builtin_nontemporal_load(csr + j + 1);
        int s2 = __builtin_nontemporal_load(csr + j + 2);
        int s3 = __builtin_nontemporal_load(csr + j + 3);
        unsigned w0 = Bp[(size_t)s0 * 8 + c], w1 = Bp[(size_t)s1 * 8 + c];
        unsigned w2 = Bp[(size_t)s2 * 8 + c], w3 = Bp[(size_t)s3 * 8 + c];
        a0 += (bflo(w0) + bflo(w1)) + (bflo(w2) + bflo(w3));
        a1 += (bfhi(w0) + bfhi(w1)) + (bfhi(w2) + bfhi(w3));
        j += 4;
    }
    for (; j < re; ++j) {
        unsigned w = Bp[(size_t)__builtin_nontemporal_load(csr + j) * 8 + c];
        a0 += bflo(w); a1 += bfhi(w);
    }
    float dv = dinv[node];
    v2f o;
    o.x = a0 * dv + bias[2 * c];
    o.y = a1 * dv + bias[2 * c + 1];
    if (relu) { o.x = fmaxf(o.x, 0.f); o.y = fmaxf(o.y, 0.f); }
    __builtin_nontemporal_store(o, (v2f*)(outp + (size_t)node * HID + 2 * c));
}

// ---------- per-graph mean-pool: register run-accumulation + span flush ----------
__global__ __launch_bounds__(256) void pool_kernel(const float* __restrict__ h,
                                                   const int* __restrict__ batch,
                                                   float* __restrict__ gsum,
                                                   float* __restrict__ cnt) {
    __shared__ float pool[N_GRAPHS * HID];  // 8 KB
    __shared__ float cntl[N_GRAPHS];
    __shared__ int gmin, gmax;
    int t = threadIdx.x;
    for (int j = t; j < N_GRAPHS * HID; j += 256) pool[j] = 0.f;
    if (t < N_GRAPHS) cntl[t] = 0.f;
    if (t == 0) { gmin = N_GRAPHS; gmax = -1; }
    __syncthreads();
    int start = blockIdx.x * 256;
    int end = min(start + 256, N_NODES);
    int c = t & 31;
    float racc = 0.f;
    int rg = -1, rcnt = 0;
    for (int nb = start + (t >> 5); nb < end; nb += 8) {
        float v = h[(size_t)nb * HID + c];
        int g = batch[nb];
        if (g != rg) {
            if ((unsigned)rg < N_GRAPHS) {
                atomicAdd(&pool[rg * HID + c], racc);
                if (c == 0) {
                    atomicAdd(&cntl[rg], (float)rcnt);
                    atomicMin(&gmin, rg); atomicMax(&gmax, rg);
                }
            }
            rg = g; racc = v; rcnt = 1;
        } else { racc += v; ++rcnt; }
    }
    if ((unsigned)rg < N_GRAPHS) {
        atomicAdd(&pool[rg * HID + c], racc);
        if (c == 0) {
            atomicAdd(&cntl[rg], (float)rcnt);
            atomicMin(&gmin, rg); atomicMax(&gmax, rg);
        }
    }
    __syncthreads();
    int lo = gmin, hi = gmax;
    if (hi >= lo) {
        int span = (hi - lo + 1) * HID;
        for (int j = t; j < span; j += 256)
            atomicAdd(&gsum[lo * HID + j], pool[lo * HID + j]);
        for (int j = t; j <= hi - lo; j += 256)
            atomicAdd(&cnt[lo + j], cntl[lo + j]);
    }
}

__global__ void summary_kernel(const float* __restrict__ gsum, const float* __restrict__ cnt,
                               const float* __restrict__ Ws, const float* __restrict__ bs,
                               float* __restrict__ out) {
    int g = blockIdx.x, c = threadIdx.x;
    float inv = 1.f / fmaxf(cnt[g], 1.f);
    float acc = bs[c];
    #pragma unroll
    for (int k = 0; k < HID; ++k)
        acc += gsum[g * HID + k] * inv * Ws[k * HID + c];
    out[g * HID + c] = acc;
}

extern "C" void kernel_launch(void* const* d_in, const int* in_sizes, int n_in,
                              void* d_out, int out_size, void* d_ws, size_t ws_size,
                              hipStream_t stream) {
    const float* x    = (const float*)d_in[0];
    const int* edge   = (const int*)d_in[1];
    const int* src    = edge;
    const int* dst    = edge + N_EDGES;
    const int* batch  = (const int*)d_in[2];
    const float* W1   = (const float*)d_in[3];
    const float* b1   = (const float*)d_in[4];
    const float* W2   = (const float*)d_in[5];
    const float* b2   = (const float*)d_in[6];
    const float* Ws   = (const float*)d_in[7];
    const float* bs   = (const float*)d_in[8];

    float* ws      = (float*)d_ws;
    unsigned* Bu1  = (unsigned*)(ws + OFF_B);      // 2 planes; H aliases head
    unsigned* Bu2  = (unsigned*)(ws + OFF_EDGEPK); // 2 planes; aliases edgepk (dead after csr2)
    int*   H       = (int*)(ws + OFF_B);
    int*   edgepk  = (int*)(ws + OFF_EDGEPK);
    int*   csr     = (int*)(ws + OFF_CSR);
    int*   colT    = (int*)(ws + OFF_COLT);
    int*   binB    = (int*)(ws + OFF_BINB);
    int*   row_ptr = (int*)(ws + OFF_ROWPTR);
    float* dinv    = ws + OFF_DINV;
    float* gsum    = ws + OFF_GS;
    float* cnt     = gsum + N_GRAPHS * HID;

    float* out     = (float*)d_out;
    float* out_sum = out;
    float* out_h   = out + N_GRAPHS * HID;

    // CSR build
    hist_kernel    <<<MGRID, 512, 0, stream>>>(dst, H);
    scanrow_kernel <<<NBIN,  512, 0, stream>>>(H, colT);
    scanbase_kernel<<<1,     512, 0, stream>>>(colT, binB, row_ptr);
    msplit_kernel  <<<MGRID, 512, 0, stream>>>(src, dst, H, binB, edgepk);
    csr2_kernel    <<<NBIN,  256, 0, stream>>>(edgepk, binB, row_ptr, dinv, csr);

    // layer 1: gemm into planes, then one L2-resident gather pass per plane
    gemm1_kernel<<<N_NODES / 32, 256, 0, stream>>>(x, W1, dinv, Bu1);
    gather_kernel<<<N_NODES / 32, 256, 0, stream>>>(Bu1,       csr, row_ptr, dinv, b1,      out_h,      1);
    gather_kernel<<<N_NODES / 32, 256, 0, stream>>>(Bu1 + PLN, csr, row_ptr, dinv, b1 + 16, out_h + 16, 1);

    // layer 2
    gemm2_kernel<<<N_NODES / 32, 256, 0, stream>>>(out_h, W2, dinv, Bu2);
    gather_kernel<<<N_NODES / 32, 256, 0, stream>>>(Bu2,       csr, row_ptr, dinv, b2,      out_h,      0);
    gather_kernel<<<N_NODES / 32, 256, 0, stream>>>(Bu2 + PLN, csr, row_ptr, dinv, b2 + 16, out_h + 16, 0);

    // pooling + summary
    hipMemsetAsync(gsum, 0, (N_GRAPHS * HID + N_GRAPHS) * sizeof(float), stream);
    pool_kernel<<<NBIN, 256, 0, stream>>>(out_h, batch, gsum, cnt);
    summary_kernel<<<N_GRAPHS, HID, 0, stream>>>(gsum, cnt, Ws, bs, out_sum);
}